// Round 5
// baseline (428.031 us; speedup 1.0000x reference)
//
#include <hip/hip_runtime.h>

#define CDIM 512
#define NDIM 4096
#define BATCH 4

using bf8v = __attribute__((ext_vector_type(8))) __bf16;
using f4v  = __attribute__((ext_vector_type(4))) float;

typedef __attribute__((address_space(1))) unsigned int gu32;
typedef __attribute__((address_space(3))) unsigned int lu32;

static __device__ __forceinline__ unsigned short f2bf(float f) {
  unsigned int u = __float_as_uint(f);
  u += 0x7fffu + ((u >> 16) & 1u);   // round-to-nearest-even
  return (unsigned short)(u >> 16);
}

// ---------------- GN pass 1: per-(b,g) mean/rstd ----------------
__global__ __launch_bounds__(256) void gn_stats_kernel(
    const float* __restrict__ x, float* __restrict__ stats) {
  const int tid = threadIdx.x;
  const float4* xv = (const float4*)(x + (long)blockIdx.x * 65536);
  float s = 0.f, ss = 0.f;
  for (int i = tid; i < 16384; i += 256) {
    float4 d = xv[i];
    s  += d.x + d.y + d.z + d.w;
    ss += d.x * d.x + d.y * d.y + d.z * d.z + d.w * d.w;
  }
#pragma unroll
  for (int off = 32; off; off >>= 1) {
    s  += __shfl_down(s, off);
    ss += __shfl_down(ss, off);
  }
  __shared__ float red[8];
  if ((tid & 63) == 0) { red[tid >> 6] = s; red[4 + (tid >> 6)] = ss; }
  __syncthreads();
  if (tid == 0) {
    float S  = red[0] + red[1] + red[2] + red[3];
    float SS = red[4] + red[5] + red[6] + red[7];
    float mean = S * (1.f / 65536.f);
    float var  = SS * (1.f / 65536.f) - mean * mean;
    stats[blockIdx.x * 2]     = mean;
    stats[blockIdx.x * 2 + 1] = rsqrtf(var + 1e-6f);
  }
}

// ---------------- GN pass 2: normalize + transpose, fp32 [C,N] -> bf16 [N,C] ----------------
__global__ __launch_bounds__(256) void gn_transpose_kernel(
    const float* __restrict__ x, const float* __restrict__ gs,
    const float* __restrict__ gb, const float* __restrict__ stats,
    unsigned short* __restrict__ hT) {
  __shared__ float t[64][65];
  const int tid = threadIdx.x;
  const int b = blockIdx.z;
  const long bbx = (long)b * ((long)CDIM * NDIM);
  const int n0 = blockIdx.x * 64, c0 = blockIdx.y * 64;
  for (int k = 0; k < 4; ++k) {
    int it = tid + k * 256;
    int c = it >> 4, no = (it & 15) << 2;
    int ch = c0 + c;
    int g = ch >> 4;
    float mean = stats[(b * 32 + g) * 2];
    float rstd = stats[(b * 32 + g) * 2 + 1];
    float a  = rstd * gs[ch];
    float bb = gb[ch] - mean * a;
    float4 d = *(const float4*)&x[bbx + (long)ch * NDIM + n0 + no];
    t[no + 0][c] = d.x * a + bb;
    t[no + 1][c] = d.y * a + bb;
    t[no + 2][c] = d.z * a + bb;
    t[no + 3][c] = d.w * a + bb;
  }
  __syncthreads();
  const long bbh = (long)b * ((long)NDIM * CDIM);
  for (int k = 0; k < 2; ++k) {
    int it = tid + k * 256;
    int n = it >> 3, co = (it & 7) << 3;
    unsigned int ow[4];
#pragma unroll
    for (int j = 0; j < 4; ++j) {
      unsigned short lo = f2bf(t[n][co + 2 * j]);
      unsigned short hi = f2bf(t[n][co + 2 * j + 1]);
      ow[j] = (unsigned int)lo | ((unsigned int)hi << 16);
    }
    uint4 o; o.x = ow[0]; o.y = ow[1]; o.z = ow[2]; o.w = ow[3];
    *(uint4*)&hT[bbh + (long)(n0 + n) * CDIM + c0 + co] = o;
  }
}

// ---------------- merged prep: wq/wk/wv fp32->bf16 + bias concat ----------------
__global__ __launch_bounds__(256) void prep_kernel(
    const float* __restrict__ wq, const float* __restrict__ wk,
    const float* __restrict__ wv, const float* __restrict__ bq,
    const float* __restrict__ bk, unsigned short* __restrict__ wqkb,
    unsigned short* __restrict__ wvb, float* __restrict__ bqk) {
  int blk = blockIdx.x;
  if (blk < 768) {
    int i = blk * 256 + threadIdx.x;          // 0..196607
    const float* src = (blk < 256) ? wq : (blk < 512) ? wk : wv;
    unsigned short* dst = (blk < 256) ? wqkb : (blk < 512) ? (wqkb + 262144) : wvb;
    int j = i - ((blk < 256) ? 0 : (blk < 512) ? 65536 : 131072);
    float4 d = ((const float4*)src)[j];
    ushort4 o;
    o.x = f2bf(d.x); o.y = f2bf(d.y); o.z = f2bf(d.z); o.w = f2bf(d.w);
    ((ushort4*)dst)[j] = o;
  } else {
#pragma unroll
    for (int k = 0; k < 4; ++k) {
      int i = threadIdx.x + k * 256;
      bqk[i] = (i < 512) ? bq[i] : bk[i - 512];
    }
  }
}

// ---------------- fp32 -> bf16 convert (wp, launched late) ----------------
__global__ __launch_bounds__(256) void cvt_kernel(
    const float* __restrict__ src, unsigned short* __restrict__ dst, int n4) {
  int i = blockIdx.x * 256 + threadIdx.x;
  if (i >= n4) return;
  float4 d = ((const float4*)src)[i];
  ushort4 o;
  o.x = f2bf(d.x); o.y = f2bf(d.y); o.z = f2bf(d.z); o.w = f2bf(d.w);
  ((ushort4*)dst)[i] = o;
}

// ---------------- NT GEMM, BK=64, XOR-swizzled LDS, global_load_lds staging ----------------
// C[M,Nn] = A[M,K] * B[Nn,K]^T, bf16 operands, row strides lA/lB.
// EPI: 0 = bf16 + bias[col]            (qk)
//      1 = bf16 + bias[row]            (v)
//      2 = bf16 exp(val*scale), row-sum atomics into rsum   (scores -> P')
//      3 = bf16 val / rsum[row]        (P'@v -> OT, fused normalize)
//      4 = fp32 + bias[row] + residual X (proj -> d_out)
// SWZ: 0 = none; 1 = PV XCD-grouping; 2 = scores group-raster.
#define BM 128
#define BN 128
#define BK 64

template <int EPI, int SWZ>
__global__ __launch_bounds__(256) void gemm_nt(
    const unsigned short* __restrict__ A, long sA, int lA,
    const unsigned short* __restrict__ B, long sB, int lB,
    void* __restrict__ Cp, long sC,
    const float* __restrict__ bias,
    const float* __restrict__ X, long sX,
    float* __restrict__ rsum,
    int Nn, int K) {
  __shared__ unsigned short As[BM * BK];   // 16 KB
  __shared__ unsigned short Bs[BN * BK];   // 16 KB
  int bx, by, bz;
  if (SWZ == 0) {
    bx = blockIdx.x; by = blockIdx.y; bz = blockIdx.z;
  } else if (SWZ == 1) {
    // groups of 4 col-blocks (same attn row-block) share flat%8 -> same XCD
    int flat = blockIdx.x;
    int q = flat >> 5, r = flat & 31;
    bx = r >> 3;
    int g = q * 8 + (r & 7);
    by = g & 31; bz = g >> 5;
  } else {
    int flat = blockIdx.x;
    bz = flat >> 10;
    int f = flat & 1023;
    by = (f & 7) + ((f >> 8) << 3);
    bx = (f >> 3) & 31;
  }
  const int tid = threadIdx.x;
  A += (long)bz * sA;
  B += (long)bz * sB;
  const int m0 = by * BM;
  const int n0 = bx * BN;
  const int lane = tid & 63;
  const int wv = tid >> 6;
  const int wm = (wv >> 1) << 6;
  const int wn = (wv & 1) << 6;
  const int l16 = lane & 15;
  const int quad = lane >> 4;
  const int sw = l16 & 7;            // fragment-read swizzle key (= row&7)
  const int r8 = lane >> 3;          // staging: row within 8-row group
  const int c8 = lane & 7;           // staging: chunk slot
  const int csw = (c8 ^ r8) << 3;    // swizzled source chunk, in elems

  f4v acc[4][4] = {};

  const unsigned short* Ag = A + (long)(m0 + wv * 32 + r8) * lA + csw;
  const unsigned short* Bg = B + (long)(n0 + wv * 32 + r8) * lB + csw;
  unsigned short* Asl = As + wv * 32 * BK;
  unsigned short* Bsl = Bs + wv * 32 * BK;

  for (int k0 = 0; k0 < K; k0 += BK) {
#pragma unroll
    for (int i = 0; i < 4; ++i) {
      __builtin_amdgcn_global_load_lds((const gu32*)(Ag + (long)i * 8 * lA + k0),
          (lu32*)(Asl + i * 512), 16, 0, 0);
      __builtin_amdgcn_global_load_lds((const gu32*)(Bg + (long)i * 8 * lB + k0),
          (lu32*)(Bsl + i * 512), 16, 0, 0);
    }
    __syncthreads();
    bf8v af[2][4], bf[2][4];
#pragma unroll
    for (int kk = 0; kk < 2; ++kk) {
#pragma unroll
      for (int t = 0; t < 4; ++t) {
        int ra = wm + t * 16 + l16;
        int rb = wn + t * 16 + l16;
        af[kk][t] = *(const bf8v*)&As[ra * BK + ((((kk << 2) + quad) ^ sw) << 3)];
        bf[kk][t] = *(const bf8v*)&Bs[rb * BK + ((((kk << 2) + quad) ^ sw) << 3)];
      }
    }
#pragma unroll
    for (int kk = 0; kk < 2; ++kk)
#pragma unroll
      for (int tm = 0; tm < 4; ++tm)
#pragma unroll
        for (int tn = 0; tn < 4; ++tn)
          acc[tm][tn] = __builtin_amdgcn_mfma_f32_16x16x32_bf16(
              af[kk][tm], bf[kk][tn], acc[kk ? tm : tm][tn] = acc[tm][tn], 0, 0, 0);
    __syncthreads();
  }

  // C/D layout (verified m89/m91): col = lane&15, row = quad*4 + reg
  if (EPI == 2) {
    // exp + store P' + row-sum atomics
#pragma unroll
    for (int tm = 0; tm < 4; ++tm) {
#pragma unroll
      for (int r = 0; r < 4; ++r) {
        const int row = m0 + wm + tm * 16 + quad * 4 + r;
        float psum = 0.f;
#pragma unroll
        for (int tn = 0; tn < 4; ++tn) {
          const int col = n0 + wn + tn * 16 + l16;
          float e = __expf(acc[tm][tn][r] * 0.044194173824159216f);
          ((unsigned short*)Cp)[(long)bz * sC + (long)row * Nn + col] = f2bf(e);
          psum += e;
        }
        psum += __shfl_xor(psum, 1);
        psum += __shfl_xor(psum, 2);
        psum += __shfl_xor(psum, 4);
        psum += __shfl_xor(psum, 8);
        if (l16 == 0) atomicAdd(&rsum[(long)bz * NDIM + row], psum);
      }
    }
  } else if (EPI == 3) {
    // normalize by row-sum
#pragma unroll
    for (int tm = 0; tm < 4; ++tm) {
#pragma unroll
      for (int r = 0; r < 4; ++r) {
        const int row = m0 + wm + tm * 16 + quad * 4 + r;
        const float inv = 1.0f / rsum[(long)bz * NDIM + row];
#pragma unroll
        for (int tn = 0; tn < 4; ++tn) {
          const int col = n0 + wn + tn * 16 + l16;
          ((unsigned short*)Cp)[(long)bz * sC + (long)row * Nn + col] =
              f2bf(acc[tm][tn][r] * inv);
        }
      }
    }
  } else {
#pragma unroll
    for (int tm = 0; tm < 4; ++tm) {
#pragma unroll
      for (int tn = 0; tn < 4; ++tn) {
        const int col = n0 + wn + tn * 16 + l16;
#pragma unroll
        for (int r = 0; r < 4; ++r) {
          const int row = m0 + wm + tm * 16 + quad * 4 + r;
          float val = acc[tm][tn][r];
          if (EPI == 0) {
            val += bias[col];
            ((unsigned short*)Cp)[(long)bz * sC + (long)row * Nn + col] = f2bf(val);
          } else if (EPI == 1) {
            val += bias[row];
            ((unsigned short*)Cp)[(long)bz * sC + (long)row * Nn + col] = f2bf(val);
          } else {
            ((float*)Cp)[(long)bz * sC + (long)row * Nn + col] =
                val + bias[row] + X[(long)bz * sX + (long)row * Nn + col];
          }
        }
      }
    }
  }
}

extern "C" void kernel_launch(void* const* d_in, const int* in_sizes, int n_in,
                              void* d_out, int out_size, void* d_ws, size_t ws_size,
                              hipStream_t stream) {
  (void)in_sizes; (void)n_in; (void)out_size;
  const float* x  = (const float*)d_in[0];
  const float* gs = (const float*)d_in[1];
  const float* gb = (const float*)d_in[2];
  const float* wq = (const float*)d_in[3];
  const float* bq = (const float*)d_in[4];
  const float* wk = (const float*)d_in[5];
  const float* bk = (const float*)d_in[6];
  const float* wv = (const float*)d_in[7];
  const float* bv = (const float*)d_in[8];
  const float* wp = (const float*)d_in[9];
  const float* bp = (const float*)d_in[10];
  float* out = (float*)d_out;

  char* ws = (char*)d_ws;
  const long NC  = (long)NDIM * CDIM;        // per-batch [N,C] elems
  const long NQK = (long)NDIM * 1024;        // per-batch [N,1024] elems
  const long BUF = NC * 2 * BATCH;           // [B,N,C] bf16 buffer = 16,777,216 B
  const long NN  = (long)NDIM * NDIM;

  // Layout (aliased):
  //   [0, BUF)        hT, later OT
  //   [BUF, 3BUF)     qkT [B,N,1024]; later wpb overlays its head
  //   [3BUF, 4BUF)    vB [B,C,N]
  //   [4BUF, ...)     sc: bf16 unnormalized exp-scores P'; head doubles as
  //                   wqkb/wvb/bqk/stats (all dead before scores GEMM writes)
  // Row-sum buffer (64 KB) lives at the head of d_out: dead until proj,
  // written by scores atomics, read by PV epilogue, then overwritten by proj.
  unsigned short* hT   = (unsigned short*)(ws);
  unsigned short* OT   = hT;
  unsigned short* qkT  = (unsigned short*)(ws + BUF);
  unsigned short* vB   = (unsigned short*)(ws + BUF * 3);
  unsigned short* sc   = (unsigned short*)(ws + BUF * 4);
  unsigned short* wqkb = sc;                                   // 1 MB
  unsigned short* wvb  = (unsigned short*)(ws + BUF * 4 + 1048576);
  float* bqk           = (float*)(ws + BUF * 4 + 1572864);
  float* stats         = (float*)(ws + BUF * 4 + 1581056);
  unsigned short* wpb  = qkT;  // overlays dead qkT for final proj
  float* rsum          = out;  // d_out head, 4*4096 floats

  gn_stats_kernel<<<BATCH * 32, 256, 0, stream>>>(x, stats);
  gn_transpose_kernel<<<dim3(NDIM / 64, CDIM / 64, BATCH), 256, 0, stream>>>(x, gs, gb, stats, hT);
  prep_kernel<<<769, 256, 0, stream>>>(wq, wk, wv, bq, bk, wqkb, wvb, bqk);
  hipMemsetAsync(rsum, 0, (size_t)BATCH * NDIM * sizeof(float), stream);

  // qkT = hT * [wq;wk]^T + bqk  ([N,1024])
  gemm_nt<0, 0><<<dim3(1024 / BN, NDIM / BM, BATCH), 256, 0, stream>>>(
      hT, NC, CDIM, wqkb, 0, CDIM, qkT, NQK, bqk, nullptr, 0, nullptr, 1024, CDIM);
  // v = wv * hT^T + bv  ([C,N])
  gemm_nt<1, 0><<<dim3(NDIM / BN, CDIM / BM, BATCH), 256, 0, stream>>>(
      wvb, 0, CDIM, hT, NC, CDIM, vB, NC, bv, nullptr, 0, nullptr, NDIM, CDIM);

  if (ws_size >= (size_t)(BUF * 4) + (size_t)(NN * 2) * BATCH) {
    // Primary (192 MiB): fully batched attention, softmax fused away.
    gemm_nt<2, 2><<<dim3(1024 * BATCH, 1, 1), 256, 0, stream>>>(
        qkT, NQK, 1024, qkT + 512, NQK, 1024, sc, NN, nullptr, nullptr, 0, rsum, NDIM, CDIM);
    gemm_nt<3, 1><<<dim3(512, 1, 1), 256, 0, stream>>>(
        sc, NN, NDIM, vB, NC, NDIM, OT, NC, nullptr, nullptr, 0, rsum, CDIM, NDIM);
  } else {
    // Fallback (~101 MB): per-batch rounds.
    for (int b = 0; b < BATCH; ++b) {
      gemm_nt<2, 2><<<dim3(1024, 1, 1), 256, 0, stream>>>(
          qkT + b * NQK, 0, 1024, qkT + b * NQK + 512, 0, 1024, sc, 0,
          nullptr, nullptr, 0, rsum + b * NDIM, NDIM, CDIM);
      gemm_nt<3, 1><<<dim3(128, 1, 1), 256, 0, stream>>>(
          sc, 0, NDIM, vB + b * NC, 0, NDIM, OT + b * NC, 0,
          nullptr, nullptr, 0, rsum + b * NDIM, CDIM, NDIM);
    }
  }

  // out = wp * OT^T + bp + x  (fp32 out, fused residual); wpb overlays dead qkT
  cvt_kernel<<<256, 256, 0, stream>>>(wp, wpb, 65536);
  gemm_nt<4, 0><<<dim3(NDIM / BN, CDIM / BM, BATCH), 256, 0, stream>>>(
      wpb, 0, CDIM, OT, NC, CDIM, out, NC, bp, x, NC, nullptr, NDIM, CDIM);
}

// Round 6
// 397.133 us; speedup vs baseline: 1.0778x; 1.0778x over previous
//
#include <hip/hip_runtime.h>

#define CDIM 512
#define NDIM 4096
#define BATCH 4

using bf8v = __attribute__((ext_vector_type(8))) __bf16;
using f4v  = __attribute__((ext_vector_type(4))) float;

typedef __attribute__((address_space(1))) unsigned int gu32;
typedef __attribute__((address_space(3))) unsigned int lu32;

static __device__ __forceinline__ unsigned short f2bf(float f) {
  unsigned int u = __float_as_uint(f);
  u += 0x7fffu + ((u >> 16) & 1u);   // round-to-nearest-even
  return (unsigned short)(u >> 16);
}

// ---------------- GN pass 1: per-(b,g) mean/rstd ----------------
__global__ __launch_bounds__(256) void gn_stats_kernel(
    const float* __restrict__ x, float* __restrict__ stats) {
  const int tid = threadIdx.x;
  const float4* xv = (const float4*)(x + (long)blockIdx.x * 65536);
  float s = 0.f, ss = 0.f;
  for (int i = tid; i < 16384; i += 256) {
    float4 d = xv[i];
    s  += d.x + d.y + d.z + d.w;
    ss += d.x * d.x + d.y * d.y + d.z * d.z + d.w * d.w;
  }
#pragma unroll
  for (int off = 32; off; off >>= 1) {
    s  += __shfl_down(s, off);
    ss += __shfl_down(ss, off);
  }
  __shared__ float red[8];
  if ((tid & 63) == 0) { red[tid >> 6] = s; red[4 + (tid >> 6)] = ss; }
  __syncthreads();
  if (tid == 0) {
    float S  = red[0] + red[1] + red[2] + red[3];
    float SS = red[4] + red[5] + red[6] + red[7];
    float mean = S * (1.f / 65536.f);
    float var  = SS * (1.f / 65536.f) - mean * mean;
    stats[blockIdx.x * 2]     = mean;
    stats[blockIdx.x * 2 + 1] = rsqrtf(var + 1e-6f);
  }
}

// ---------------- GN pass 2: normalize + transpose, fp32 [C,N] -> bf16 [N,C] ----------------
__global__ __launch_bounds__(256) void gn_transpose_kernel(
    const float* __restrict__ x, const float* __restrict__ gs,
    const float* __restrict__ gb, const float* __restrict__ stats,
    unsigned short* __restrict__ hT) {
  __shared__ float t[64][65];
  const int tid = threadIdx.x;
  const int b = blockIdx.z;
  const long bbx = (long)b * ((long)CDIM * NDIM);
  const int n0 = blockIdx.x * 64, c0 = blockIdx.y * 64;
  for (int k = 0; k < 4; ++k) {
    int it = tid + k * 256;
    int c = it >> 4, no = (it & 15) << 2;
    int ch = c0 + c;
    int g = ch >> 4;
    float mean = stats[(b * 32 + g) * 2];
    float rstd = stats[(b * 32 + g) * 2 + 1];
    float a  = rstd * gs[ch];
    float bb = gb[ch] - mean * a;
    float4 d = *(const float4*)&x[bbx + (long)ch * NDIM + n0 + no];
    t[no + 0][c] = d.x * a + bb;
    t[no + 1][c] = d.y * a + bb;
    t[no + 2][c] = d.z * a + bb;
    t[no + 3][c] = d.w * a + bb;
  }
  __syncthreads();
  const long bbh = (long)b * ((long)NDIM * CDIM);
  for (int k = 0; k < 2; ++k) {
    int it = tid + k * 256;
    int n = it >> 3, co = (it & 7) << 3;
    unsigned int ow[4];
#pragma unroll
    for (int j = 0; j < 4; ++j) {
      unsigned short lo = f2bf(t[n][co + 2 * j]);
      unsigned short hi = f2bf(t[n][co + 2 * j + 1]);
      ow[j] = (unsigned int)lo | ((unsigned int)hi << 16);
    }
    uint4 o; o.x = ow[0]; o.y = ow[1]; o.z = ow[2]; o.w = ow[3];
    *(uint4*)&hT[bbh + (long)(n0 + n) * CDIM + c0 + co] = o;
  }
}

// ---------------- merged prep: wq/wk/wv fp32->bf16 + bias concat ----------------
__global__ __launch_bounds__(256) void prep_kernel(
    const float* __restrict__ wq, const float* __restrict__ wk,
    const float* __restrict__ wv, const float* __restrict__ bq,
    const float* __restrict__ bk, unsigned short* __restrict__ wqkb,
    unsigned short* __restrict__ wvb, float* __restrict__ bqk) {
  int blk = blockIdx.x;
  if (blk < 768) {
    int i = blk * 256 + threadIdx.x;
    const float* src = (blk < 256) ? wq : (blk < 512) ? wk : wv;
    unsigned short* dst = (blk < 256) ? wqkb : (blk < 512) ? (wqkb + 262144) : wvb;
    int j = i - ((blk < 256) ? 0 : (blk < 512) ? 65536 : 131072);
    float4 d = ((const float4*)src)[j];
    ushort4 o;
    o.x = f2bf(d.x); o.y = f2bf(d.y); o.z = f2bf(d.z); o.w = f2bf(d.w);
    ((ushort4*)dst)[j] = o;
  } else {
#pragma unroll
    for (int k = 0; k < 4; ++k) {
      int i = threadIdx.x + k * 256;
      bqk[i] = (i < 512) ? bq[i] : bk[i - 512];
    }
  }
}

// ---------------- fp32 -> bf16 convert (wp, launched late) ----------------
__global__ __launch_bounds__(256) void cvt_kernel(
    const float* __restrict__ src, unsigned short* __restrict__ dst, int n4) {
  int i = blockIdx.x * 256 + threadIdx.x;
  if (i >= n4) return;
  float4 d = ((const float4*)src)[i];
  ushort4 o;
  o.x = f2bf(d.x); o.y = f2bf(d.y); o.z = f2bf(d.z); o.w = f2bf(d.w);
  ((ushort4*)dst)[i] = o;
}

// ---------------- NT GEMM, BK=64, XOR-swizzled LDS, global_load_lds staging ----------------
// C[M,Nn] = A[M,K] * B[Nn,K]^T, bf16 operands, row strides lA/lB.
// EPI: 0 = bf16 + bias[col]            (qk)
//      1 = bf16 + bias[row]            (v)
//      2 = bf16 exp(val*scale)         (scores -> P', unnormalized)
//      3 = bf16 val / rsum[row]        (P'@v; rsum computed in-register via ones-MFMA)
//      4 = fp32 + bias[row] + residual X (proj -> d_out)
// SWZ: 0 = none; 1 = PV XCD-grouping; 2 = scores group-raster.
#define BM 128
#define BN 128
#define BK 64

template <int EPI, int SWZ>
__global__ __launch_bounds__(256) void gemm_nt(
    const unsigned short* __restrict__ A, long sA, int lA,
    const unsigned short* __restrict__ B, long sB, int lB,
    void* __restrict__ Cp, long sC,
    const float* __restrict__ bias,
    const float* __restrict__ X, long sX,
    int Nn, int K) {
  __shared__ unsigned short As[BM * BK];   // 16 KB
  __shared__ unsigned short Bs[BN * BK];   // 16 KB
  int bx, by, bz;
  if (SWZ == 0) {
    bx = blockIdx.x; by = blockIdx.y; bz = blockIdx.z;
  } else if (SWZ == 1) {
    // groups of 4 col-blocks (same attn row-block) share flat%8 -> same XCD
    int flat = blockIdx.x;
    int q = flat >> 5, r = flat & 31;
    bx = r >> 3;
    int g = q * 8 + (r & 7);
    by = g & 31; bz = g >> 5;
  } else {
    int flat = blockIdx.x;
    bz = flat >> 10;
    int f = flat & 1023;
    by = (f & 7) + ((f >> 8) << 3);
    bx = (f >> 3) & 31;
  }
  const int tid = threadIdx.x;
  A += (long)bz * sA;
  B += (long)bz * sB;
  const int m0 = by * BM;
  const int n0 = bx * BN;
  const int lane = tid & 63;
  const int wv = tid >> 6;
  const int wm = (wv >> 1) << 6;
  const int wn = (wv & 1) << 6;
  const int l16 = lane & 15;
  const int quad = lane >> 4;
  const int sw = l16 & 7;            // fragment-read swizzle key (= row&7)
  const int r8 = lane >> 3;          // staging: row within 8-row group
  const int c8 = lane & 7;           // staging: chunk slot
  const int csw = (c8 ^ r8) << 3;    // swizzled source chunk, in elems

  f4v acc[4][4] = {};
  f4v accr[4] = {};                  // EPI==3: row-sum accumulators (ones-MFMA)
  bf8v ones;
#pragma unroll
  for (int i = 0; i < 8; ++i) ones[i] = (__bf16)1.0f;

  const unsigned short* Ag = A + (long)(m0 + wv * 32 + r8) * lA + csw;
  const unsigned short* Bg = B + (long)(n0 + wv * 32 + r8) * lB + csw;
  unsigned short* Asl = As + wv * 32 * BK;
  unsigned short* Bsl = Bs + wv * 32 * BK;

  for (int k0 = 0; k0 < K; k0 += BK) {
#pragma unroll
    for (int i = 0; i < 4; ++i) {
      __builtin_amdgcn_global_load_lds((const gu32*)(Ag + (long)i * 8 * lA + k0),
          (lu32*)(Asl + i * 512), 16, 0, 0);
      __builtin_amdgcn_global_load_lds((const gu32*)(Bg + (long)i * 8 * lB + k0),
          (lu32*)(Bsl + i * 512), 16, 0, 0);
    }
    __syncthreads();
    bf8v af[2][4], bf[2][4];
#pragma unroll
    for (int kk = 0; kk < 2; ++kk) {
#pragma unroll
      for (int t = 0; t < 4; ++t) {
        int ra = wm + t * 16 + l16;
        int rb = wn + t * 16 + l16;
        af[kk][t] = *(const bf8v*)&As[ra * BK + ((((kk << 2) + quad) ^ sw) << 3)];
        bf[kk][t] = *(const bf8v*)&Bs[rb * BK + ((((kk << 2) + quad) ^ sw) << 3)];
      }
    }
#pragma unroll
    for (int kk = 0; kk < 2; ++kk) {
#pragma unroll
      for (int tm = 0; tm < 4; ++tm) {
#pragma unroll
        for (int tn = 0; tn < 4; ++tn)
          acc[tm][tn] = __builtin_amdgcn_mfma_f32_16x16x32_bf16(
              af[kk][tm], bf[kk][tn], acc[tm][tn], 0, 0, 0);
        if (EPI == 3)
          accr[tm] = __builtin_amdgcn_mfma_f32_16x16x32_bf16(
              af[kk][tm], ones, accr[tm], 0, 0, 0);
      }
    }
    __syncthreads();
  }

  // C/D layout (verified m89/m91): col = lane&15, row = quad*4 + reg
  if (EPI == 2) {
    // exp + store P' (unnormalized); row-sums handled in PV via ones-MFMA
#pragma unroll
    for (int tm = 0; tm < 4; ++tm) {
#pragma unroll
      for (int r = 0; r < 4; ++r) {
        const int row = m0 + wm + tm * 16 + quad * 4 + r;
#pragma unroll
        for (int tn = 0; tn < 4; ++tn) {
          const int col = n0 + wn + tn * 16 + l16;
          float e = __expf(acc[tm][tn][r] * 0.044194173824159216f);
          ((unsigned short*)Cp)[(long)bz * sC + (long)row * Nn + col] = f2bf(e);
        }
      }
    }
  } else if (EPI == 3) {
    // normalize by in-register row-sum (accr: all 16 cols identical = rsum)
#pragma unroll
    for (int tm = 0; tm < 4; ++tm) {
#pragma unroll
      for (int r = 0; r < 4; ++r) {
        const int row = m0 + wm + tm * 16 + quad * 4 + r;
        const float inv = 1.0f / accr[tm][r];
#pragma unroll
        for (int tn = 0; tn < 4; ++tn) {
          const int col = n0 + wn + tn * 16 + l16;
          ((unsigned short*)Cp)[(long)bz * sC + (long)row * Nn + col] =
              f2bf(acc[tm][tn][r] * inv);
        }
      }
    }
  } else {
#pragma unroll
    for (int tm = 0; tm < 4; ++tm) {
#pragma unroll
      for (int tn = 0; tn < 4; ++tn) {
        const int col = n0 + wn + tn * 16 + l16;
#pragma unroll
        for (int r = 0; r < 4; ++r) {
          const int row = m0 + wm + tm * 16 + quad * 4 + r;
          float val = acc[tm][tn][r];
          if (EPI == 0) {
            val += bias[col];
            ((unsigned short*)Cp)[(long)bz * sC + (long)row * Nn + col] = f2bf(val);
          } else if (EPI == 1) {
            val += bias[row];
            ((unsigned short*)Cp)[(long)bz * sC + (long)row * Nn + col] = f2bf(val);
          } else {
            ((float*)Cp)[(long)bz * sC + (long)row * Nn + col] =
                val + bias[row] + X[(long)bz * sX + (long)row * Nn + col];
          }
        }
      }
    }
  }
}

extern "C" void kernel_launch(void* const* d_in, const int* in_sizes, int n_in,
                              void* d_out, int out_size, void* d_ws, size_t ws_size,
                              hipStream_t stream) {
  (void)in_sizes; (void)n_in; (void)out_size;
  const float* x  = (const float*)d_in[0];
  const float* gs = (const float*)d_in[1];
  const float* gb = (const float*)d_in[2];
  const float* wq = (const float*)d_in[3];
  const float* bq = (const float*)d_in[4];
  const float* wk = (const float*)d_in[5];
  const float* bk = (const float*)d_in[6];
  const float* wv = (const float*)d_in[7];
  const float* bv = (const float*)d_in[8];
  const float* wp = (const float*)d_in[9];
  const float* bp = (const float*)d_in[10];
  float* out = (float*)d_out;

  char* ws = (char*)d_ws;
  const long NC  = (long)NDIM * CDIM;        // per-batch [N,C] elems
  const long NQK = (long)NDIM * 1024;        // per-batch [N,1024] elems
  const long BUF = NC * 2 * BATCH;           // [B,N,C] bf16 buffer = 16,777,216 B
  const long NN  = (long)NDIM * NDIM;

  // Layout (aliased):
  //   [0, BUF)        hT, later OT
  //   [BUF, 3BUF)     qkT [B,N,1024]; later wpb overlays its head
  //   [3BUF, 4BUF)    vB [B,C,N]
  //   [4BUF, ...)     sc: bf16 unnormalized exp-scores P'; head doubles as
  //                   wqkb/wvb/bqk/stats (all dead before scores GEMM writes)
  unsigned short* hT   = (unsigned short*)(ws);
  unsigned short* OT   = hT;
  unsigned short* qkT  = (unsigned short*)(ws + BUF);
  unsigned short* vB   = (unsigned short*)(ws + BUF * 3);
  unsigned short* sc   = (unsigned short*)(ws + BUF * 4);
  unsigned short* wqkb = sc;                                   // 1 MB
  unsigned short* wvb  = (unsigned short*)(ws + BUF * 4 + 1048576);
  float* bqk           = (float*)(ws + BUF * 4 + 1572864);
  float* stats         = (float*)(ws + BUF * 4 + 1581056);
  unsigned short* wpb  = qkT;  // overlays dead qkT for final proj

  gn_stats_kernel<<<BATCH * 32, 256, 0, stream>>>(x, stats);
  gn_transpose_kernel<<<dim3(NDIM / 64, CDIM / 64, BATCH), 256, 0, stream>>>(x, gs, gb, stats, hT);
  prep_kernel<<<769, 256, 0, stream>>>(wq, wk, wv, bq, bk, wqkb, wvb, bqk);

  // qkT = hT * [wq;wk]^T + bqk  ([N,1024])
  gemm_nt<0, 0><<<dim3(1024 / BN, NDIM / BM, BATCH), 256, 0, stream>>>(
      hT, NC, CDIM, wqkb, 0, CDIM, qkT, NQK, bqk, nullptr, 0, 1024, CDIM);
  // v = wv * hT^T + bv  ([C,N])
  gemm_nt<1, 0><<<dim3(NDIM / BN, CDIM / BM, BATCH), 256, 0, stream>>>(
      wvb, 0, CDIM, hT, NC, CDIM, vB, NC, bv, nullptr, 0, NDIM, CDIM);

  if (ws_size >= (size_t)(BUF * 4) + (size_t)(NN * 2) * BATCH) {
    // Primary (192 MiB): fully batched attention, softmax fused away.
    gemm_nt<2, 2><<<dim3(1024 * BATCH, 1, 1), 256, 0, stream>>>(
        qkT, NQK, 1024, qkT + 512, NQK, 1024, sc, NN, nullptr, nullptr, 0, NDIM, CDIM);
    gemm_nt<3, 1><<<dim3(512, 1, 1), 256, 0, stream>>>(
        sc, NN, NDIM, vB, NC, NDIM, OT, NC, nullptr, nullptr, 0, CDIM, NDIM);
  } else {
    // Fallback (~101 MB): per-batch rounds.
    for (int b = 0; b < BATCH; ++b) {
      gemm_nt<2, 2><<<dim3(1024, 1, 1), 256, 0, stream>>>(
          qkT + b * NQK, 0, 1024, qkT + b * NQK + 512, 0, 1024, sc, 0,
          nullptr, nullptr, 0, NDIM, CDIM);
      gemm_nt<3, 1><<<dim3(128, 1, 1), 256, 0, stream>>>(
          sc, 0, NDIM, vB + b * NC, 0, NDIM, OT + b * NC, 0,
          nullptr, nullptr, 0, CDIM, NDIM);
    }
  }

  // out = wp * OT^T + bp + x  (fp32 out, fused residual); wpb overlays dead qkT
  cvt_kernel<<<256, 256, 0, stream>>>(wp, wpb, 65536);
  gemm_nt<4, 0><<<dim3(NDIM / BN, CDIM / BM, BATCH), 256, 0, stream>>>(
      wpb, 0, CDIM, OT, NC, CDIM, out, NC, bp, x, NC, NDIM, CDIM);
}